// Round 13
// baseline (773.574 us; speedup 1.0000x reference)
//
#include <hip/hip_runtime.h>

#define NEG 0.01f
__device__ __forceinline__ float lrelu(float v){ return v >= 0.f ? v : NEG * v; }

typedef short bf16x8 __attribute__((ext_vector_type(8)));   // 8 bf16 = 4 VGPRs
typedef float f32x4 __attribute__((ext_vector_type(4)));
typedef unsigned short u16;

__device__ __forceinline__ u16 f2bf(float f) {   // RNE f32 -> bf16 (finite inputs)
  unsigned u = __float_as_uint(f);
  return (u16)((u + 0x7FFFu + ((u >> 16) & 1u)) >> 16);
}
__device__ __forceinline__ float bflo(unsigned u){ return __uint_as_float(u << 16); }
__device__ __forceinline__ float bfhi(unsigned u){ return __uint_as_float(u & 0xffff0000u); }
__device__ __forceinline__ float bfu(u16 v){ return __uint_as_float((unsigned)v << 16); }

__device__ __forceinline__ float fma4(float4 wv, float4 hv, float acc) {
  return fmaf(wv.x, hv.x, fmaf(wv.y, hv.y, fmaf(wv.z, hv.z, fmaf(wv.w, hv.w, acc))));
}

// ============================ RULES (carried) ============================
// (R2)  no runtime-bound loop may index a register array — full unroll only.
// (R9)  dense head: ONE wave per patch (s_waitcnt+wave_barrier ordering).
// (R14) MFMA 16x16x32 bf16 map (verified): A row m=l&15, k=8*(l>>4)+i; B col
//       n=l&15; C/D row=(l>>4)*4+reg, col=l&15. Garbage rows safe (discard).
// (R15) H2 bf16 from birth; residual rounds ONCE.
// (R16) VGPR cliff at 64. PROVEN r11: nothing live across barriers + hard cap
//       -> 44-56 VGPR, no spill. Keep both.
// (R20) SERIAL p-loops in the same waves add zero overlap (r4). r13's form is
//       PARALLEL across waves — different mechanism (barrier amortization).
// (R22) unroll-1 on HOT weight loops serializes latency; dense head unroll 4.
// (R24) stage-2a = MFMA GEMM [81x64]x[64x96] (T|P|G); G -> LDS bf16 stash.
// (R25) H2B row stride 36 u32 (144B): MFMA A-reads ~2-way; st-1 writes <=2-way.
// (R26) split retired (r7: back block = 51us pure overhead, 191MB trip).
// (R27) stash regions FULL size (r8 overlap bug).
// (R28) stage-4 = MFMA [81x32]x[32x64]; A = bf16(attn*G) built in-reg.
// (R29) stage-4 BARRIER-FREE: in-place H2B RMW on wave-own rows.
// (R30) SBH/G bf16 [81][40]: arena 6156 dw/patch.
// (R31) CONCURRENCY LEVER IS SPENT: r11(+35% C)->+6.7%, r12(+21% C)->+0.0%.
//       All pipes <30% busy; limiter = per-block serial envelope (11 barrier-
//       separated chains). r13: TWO patches per block PARALLEL ACROSS WAVES
//       (512 thr; waves 0-3 patch A arena 0, waves 4-7 patch B arena 1).
//       Barrier events per patch halve; cross-patch waves hide each other's
//       post-barrier latency. Numerics identical -> absmax must stay 3.05e-5.

// -------- LDS: TWO arenas of 6156 dw; S[12312] = 49248 B -> 3 blocks/CU ----
// Per-arena offsets (add base = half*6156):
// Phase A (0-4): H2B@0 u32[81][36] (2916) | SBH@2916 u16[81][40] (1620) |
//   XS@4536(121, dies st-1) | G@4536 u16[81][40] (1620, born 2a after XS dead).
// Stage 4: in-place H2B->H4 u16[81][72] @0 (R29, no barrier).
// Stage 5: A-reads H4@0 stride 144B (garbage rows <=101 -> dw <=3676 < 6156,
//   in-arena, discarded), writes C2S@2916 (1792, over dead SBH+G).
// Phase C: P6@0(1600) C3S@1600(200) D1P@1800(256) D1@2056 D2@2120 D3@2152
//   D4@2168; C2S@2916 read by stage 6.
#define ARENA 6156
#define H2B  0
#define SBH  2916
#define XS   4536
#define G0   4536
#define H4   0
#define C2S  2916
#define P6   0
#define C3S  1600
#define D1P  1800
#define D1   2056
#define D2   2120
#define D3   2152
#define D4   2168

// repack: w2 -> wb2 bf16 [tap9][oc32][ic64] (18432 u16, dw 0..9215)
//         w3 -> pw3 fp32 [ic32][oc8][12] (3072 dw at 9216)
//         wt/wp/wg -> wtpg bf16 [96 n][64 k] (6144 u16, dw 12288..15359)
//         wo -> wob bf16 [64 n][32 k] (2048 u16, dw 15360..16383)
__global__ void repack_w23(const float* __restrict__ w2, const float* __restrict__ w3,
                           const float* __restrict__ wt, const float* __restrict__ wp,
                           const float* __restrict__ wg, const float* __restrict__ wo,
                           float* __restrict__ pw) {
  int idx = blockIdx.x * 256 + threadIdx.x;
  u16* u = (u16*)pw;
  for (int i = idx; i < 18432 + 3072 + 6144 + 2048; i += gridDim.x * 256) {
    if (i < 18432) {
      int ic = i & 63, oc = (i >> 6) & 31, tap = i >> 11;
      u[i] = f2bf(w2[(oc * 64 + ic) * 9 + tap]);
    } else if (i < 18432 + 3072) {
      int j = i - 18432;
      int s = j % 12, rest = j / 12, oc = rest & 7, ic = rest >> 3;
      pw[9216 + j] = (s < 9) ? w3[(oc * 32 + ic) * 9 + s] : 0.f;
    } else if (i < 18432 + 3072 + 6144) {
      int j = i - 21504;                 // wtpg
      int k = j & 63, n = j >> 6;
      float v = (n < 32) ? wt[n * 64 + k]
              : (n < 64) ? wp[(n - 32) * 64 + k]
                         : wg[(n - 64) * 64 + k];
      u[24576 + j] = f2bf(v);
    } else {
      int j = i - 27648;                 // wob: [oc][ic]
      u[30720 + j] = f2bf(wo[j]);
    }
  }
}

// stage-4 A-fragment: bf16(attn*G), both operands bf16 in LDS (R28/R30)
__device__ __forceinline__ bf16x8 st4_afrag(const float* SA, int ar, int kg) {
  const uint4 sv = *(const uint4*)((const u16*)&SA[SBH] + ar * 40 + kg * 8);
  const uint4 gv = *(const uint4*)((const u16*)&SA[G0] + ar * 40 + kg * 8);
  unsigned q0 = (unsigned)f2bf(bflo(sv.x) * bflo(gv.x)) |
                ((unsigned)f2bf(bfhi(sv.x) * bfhi(gv.x)) << 16);
  unsigned q1 = (unsigned)f2bf(bflo(sv.y) * bflo(gv.y)) |
                ((unsigned)f2bf(bfhi(sv.y) * bfhi(gv.y)) << 16);
  unsigned q2 = (unsigned)f2bf(bflo(sv.z) * bflo(gv.z)) |
                ((unsigned)f2bf(bfhi(sv.z) * bfhi(gv.z)) << 16);
  unsigned q3 = (unsigned)f2bf(bflo(sv.w) * bflo(gv.w)) |
                ((unsigned)f2bf(bfhi(sv.w) * bfhi(gv.w)) << 16);
  union { uint4 u; bf16x8 b; } v; v.u = (uint4){q0, q1, q2, q3}; return v.b;
}

__global__ __launch_bounds__(512, 8) __attribute__((amdgpu_num_vgpr(64)))
void braggnn_fused(
    const float* __restrict__ x,
    const float* __restrict__ w1, const float* __restrict__ b1,
    const u16* __restrict__ wtpg,
    const float* __restrict__ bt, const float* __restrict__ bp,
    const float* __restrict__ bg,
    const u16* __restrict__ wob, const float* __restrict__ bo,
    const u16* __restrict__ wb2, const float* __restrict__ pw3,
    const float* __restrict__ b2, const float* __restrict__ b3,
    const float* __restrict__ dw1, const float* __restrict__ db1,
    const float* __restrict__ dw2, const float* __restrict__ db2,
    const float* __restrict__ dw3, const float* __restrict__ db3,
    const float* __restrict__ dw4, const float* __restrict__ db4,
    const float* __restrict__ dw5, const float* __restrict__ db5,
    float* __restrict__ out, int nP)
{
  const int half = threadIdx.x >> 8;          // 0: waves 0-3, 1: waves 4-7
  const int tl = threadIdx.x & 255;           // per-patch thread id (R31)
  int p = 2 * blockIdx.x + half;
  const int pvalid = (p < nP);
  if (!pvalid) p = nP - 1;                    // duplicate work, writes guarded

  __shared__ __align__(16) float S[2 * ARENA];   // 49248 B
  float* SA = S + half * ARENA;

  // ---- stage 0: load 11x11 patch (per half) ----
  if (tl < 121) SA[XS + tl] = x[(size_t)p * 121 + tl];
  __syncthreads();

  // ---- stage 1: conv1 1->64 3x3, oc-PAIRED -> H2B bf16 [81][72s36] (R15/R25) ----
  {
    const int ocp = tl & 31, pg = tl >> 5;     // oc = 2*ocp, 2*ocp+1; pg 0..7
    float wreg[18];
#pragma unroll
    for (int i = 0; i < 18; i++) wreg[i] = w1[ocp * 18 + i];
    const float bv0 = b1[2 * ocp], bv1 = b1[2 * ocp + 1];
    for (int px = pg; px < 81; px += 8) {
      const int y = px / 9, xx = px - y * 9;
      const float* xr = &SA[XS + y * 11 + xx];
      float a0 = bv0, a1 = bv1;
#pragma unroll
      for (int ky = 0; ky < 3; ky++)
#pragma unroll
        for (int kx = 0; kx < 3; kx++) {
          const float v = xr[ky * 11 + kx];
          a0 = fmaf(v, wreg[ky * 3 + kx], a0);
          a1 = fmaf(v, wreg[9 + ky * 3 + kx], a1);
        }
      ((unsigned*)SA)[H2B + px * 36 + ocp] =
          (unsigned)f2bf(a0) | ((unsigned)f2bf(a1) << 16);
    }
  }
  __syncthreads();

  // ---- stage 2a (R24): theta/phi/g via MFMA; logits -> SBH bf16, g -> G ----
  {
    const int lane = tl & 63, wid = tl >> 6;
    const int c = lane & 15, kg = lane >> 4;
    const char* Sb = (const char*)SA;         // H2B at byte 0, 144 B/row
    u16* SBu = (u16*)&SA[SBH];
    u16* Gp  = (u16*)&SA[G0];
#pragma unroll 1
    for (int r2 = 0; r2 < 2; r2++) {
      const int mt = wid + 4 * r2;
      if (mt >= 6) break;                     // wave-uniform
      const int arow = mt * 16 + c;           // px (rows 81-95: garbage, discarded)
      const bf16x8 a0 = *(const bf16x8*)(Sb + arow * 144 + kg * 16);
      const bf16x8 a1 = *(const bf16x8*)(Sb + arow * 144 + 64 + kg * 16);
#pragma unroll
      for (int ng = 0; ng < 2; ng++) {
        const u16* bl = wtpg + (ng * 16 + c) * 64 + kg * 8;
        const bf16x8 t0 = *(const bf16x8*)(bl);
        const bf16x8 t1 = *(const bf16x8*)(bl + 32);
        const bf16x8 p0 = *(const bf16x8*)(bl + 2048);       // +32 n
        const bf16x8 p1 = *(const bf16x8*)(bl + 2048 + 32);
        const bf16x8 g0 = *(const bf16x8*)(bl + 4096);       // +64 n
        const bf16x8 g1 = *(const bf16x8*)(bl + 4096 + 32);
        f32x4 aT = {0.f,0.f,0.f,0.f}, aP = {0.f,0.f,0.f,0.f}, aG = {0.f,0.f,0.f,0.f};
        aT = __builtin_amdgcn_mfma_f32_16x16x32_bf16(a0, t0, aT, 0, 0, 0);
        aT = __builtin_amdgcn_mfma_f32_16x16x32_bf16(a1, t1, aT, 0, 0, 0);
        aP = __builtin_amdgcn_mfma_f32_16x16x32_bf16(a0, p0, aP, 0, 0, 0);
        aP = __builtin_amdgcn_mfma_f32_16x16x32_bf16(a1, p1, aP, 0, 0, 0);
        aG = __builtin_amdgcn_mfma_f32_16x16x32_bf16(a0, g0, aG, 0, 0, 0);
        aG = __builtin_amdgcn_mfma_f32_16x16x32_bf16(a1, g1, aG, 0, 0, 0);
        const int oc = ng * 16 + c;
        const float bT = bt[oc], bP = bp[oc], bG = bg[oc];
#pragma unroll
        for (int r = 0; r < 4; r++) {
          const int px = mt * 16 + kg * 4 + r;  // C row = (l>>4)*4 + reg (R14)
          if (px <= 80) {
            SBu[px * 40 + oc] = f2bf((aT[r] + bT) * (aP[r] + bP));   // R30
            Gp[px * 40 + oc]  = f2bf(aG[r] + bG);
          }
        }
      }
    }
  }
  __syncthreads();

  // ---- stage 2 pass B: softmax over W (9), bf16 in/out, f32 compute (R30) ----
  {
    u16* SBu = (u16*)&SA[SBH];
    auto sm = [&](int r) {
      const int oc = r & 31, y = r >> 5;
      const int base = y * 9 * 40 + oc;       // u16 index; px = y*9+k
      float v[9]; float m = -1e30f;
#pragma unroll
      for (int k = 0; k < 9; k++) { v[k] = bfu(SBu[base + k * 40]); m = fmaxf(m, v[k]); }
      float s = 0.f;
#pragma unroll
      for (int k = 0; k < 9; k++) { v[k] = __expf(v[k] - m); s += v[k]; }
      const float inv = 1.f / s;
#pragma unroll
      for (int k = 0; k < 9; k++) SBu[base + k * 40] = f2bf(v[k] * inv);
    };
    sm(tl);
    if (tl < 32) sm(256 + tl);
  }
  __syncthreads();

  // ---- stage 4 (R28/R29): wo 1x1 as MFMA, BARRIER-FREE, in-place H2B RMW ----
  {
    const int lane = tl & 63, wid = tl >> 6;
    const int c = lane & 15, kg = lane >> 4;
    const u16* wbp = wob + c * 32 + kg * 8;
    const bf16x8 b0 = *(const bf16x8*)(wbp);
    const bf16x8 b1 = *(const bf16x8*)(wbp + 512);    // +16 n
    const bf16x8 b2 = *(const bf16x8*)(wbp + 1024);   // +32 n
    const bf16x8 b3 = *(const bf16x8*)(wbp + 1536);   // +48 n
    const f32x4 z = {0.f, 0.f, 0.f, 0.f};
    u16* Hw = (u16*)SA;     // H2B/H4 u16 view: idx = px*72 + oc (same address!)
#define ST4EPI(MT, ACC, NT) { \
      const int oc_ = (NT) * 16 + c; \
      const float bov_ = bo[oc_]; \
      _Pragma("unroll") \
      for (int r = 0; r < 4; r++) { \
        const int px_ = (MT) * 16 + kg * 4 + r; \
        if (px_ <= 80) { \
          const int idx_ = px_ * 72 + oc_; \
          Hw[idx_] = f2bf(lrelu((ACC[r] + bfu(Hw[idx_])) + bov_)); \
        } \
      } }
    {   // m-tile 0: rows [16*wid, 16*wid+16) — own rows only (R29)
      const bf16x8 a0 = st4_afrag(SA, wid * 16 + c, kg);
      f32x4 A0 = __builtin_amdgcn_mfma_f32_16x16x32_bf16(a0, b0, z, 0, 0, 0);
      f32x4 A1 = __builtin_amdgcn_mfma_f32_16x16x32_bf16(a0, b1, z, 0, 0, 0);
      f32x4 A2 = __builtin_amdgcn_mfma_f32_16x16x32_bf16(a0, b2, z, 0, 0, 0);
      f32x4 A3 = __builtin_amdgcn_mfma_f32_16x16x32_bf16(a0, b3, z, 0, 0, 0);
      ST4EPI(wid, A0, 0) ST4EPI(wid, A1, 1) ST4EPI(wid, A2, 2) ST4EPI(wid, A3, 3)
    }
    if (wid < 2) {   // m-tile 1: rows [16*(wid+4), ...) clamped to 80
      int ar1 = (wid + 4) * 16 + c; if (ar1 > 80) ar1 = 80;
      const bf16x8 a1 = st4_afrag(SA, ar1, kg);
      f32x4 A0 = __builtin_amdgcn_mfma_f32_16x16x32_bf16(a1, b0, z, 0, 0, 0);
      f32x4 A1 = __builtin_amdgcn_mfma_f32_16x16x32_bf16(a1, b1, z, 0, 0, 0);
      f32x4 A2 = __builtin_amdgcn_mfma_f32_16x16x32_bf16(a1, b2, z, 0, 0, 0);
      f32x4 A3 = __builtin_amdgcn_mfma_f32_16x16x32_bf16(a1, b3, z, 0, 0, 0);
      const int mtB = wid + 4;
      ST4EPI(mtB, A0, 0) ST4EPI(mtB, A1, 1) ST4EPI(mtB, A2, 2) ST4EPI(mtB, A3, 3)
    }
  }
  __syncthreads();

  // ---- stage 5 (R14): conv2 64->32 3x3 as bf16 MFMA 16x16x32 ----
  {
    const int lane = tl & 63, wid = tl >> 6;
    const int m = lane & 15, kg = lane >> 4;      // A row, k-group
    const int opx = wid * 16 + m;                 // output px this lane feeds
    const int oy = opx / 7, ox = opx - oy * 7;
    const char* Sb = (const char*)SA;
    int aoff = (oy * 9 + ox) * 144 + kg * 16;     // bytes into H4@0 (144 B/row)
    const u16* wbl = wb2 + (lane & 15) * 64 + kg * 8;
    f32x4 acc0 = {0.f, 0.f, 0.f, 0.f}, acc1 = {0.f, 0.f, 0.f, 0.f};
#pragma unroll 1
    for (int ky = 0; ky < 3; ky++) {
#pragma unroll
      for (int kx = 0; kx < 3; kx++) {
#pragma unroll
        for (int ks = 0; ks < 2; ks++) {
          const bf16x8 av = *(const bf16x8*)(Sb + (aoff + kx * 144 + ks * 64));
          const bf16x8 b0v = *(const bf16x8*)(wbl + kx * 2048 + ks * 32);
          const bf16x8 b1v = *(const bf16x8*)(wbl + kx * 2048 + ks * 32 + 1024);
          acc0 = __builtin_amdgcn_mfma_f32_16x16x32_bf16(av, b0v, acc0, 0, 0, 0);
          acc1 = __builtin_amdgcn_mfma_f32_16x16x32_bf16(av, b1v, acc1, 0, 0, 0);
        }
      }
      aoff += 9 * 144;        // next ky input row
      wbl  += 3 * 2048;       // next ky tap group
    }
    // epilogue: bias + lrelu -> C2S@2916 (over dead SBH+G; disjoint from
    // live H4@0..2915). Garbage A-reads into C2S region are discarded rows.
#pragma unroll
    for (int nt = 0; nt < 2; nt++) {
      const f32x4 accv = nt ? acc1 : acc0;
      const int oc = nt * 16 + (lane & 15);
      const float bv = b2[oc];
#pragma unroll
      for (int r = 0; r < 4; r++) {
        const int px = wid * 16 + kg * 4 + r;     // C row = (lane>>4)*4 + reg
        if (px < 49) {
          const int y = px / 7, xx = px - y * 7;
          SA[C2S + oc * 56 + y * 8 + xx] = lrelu(accv[r] + bv);
        }
      }
    }
  }
  __syncthreads();

  // ---- stage 6: conv3 32->8 3x3, K split in 8 groups of 4 ic ----
  {
    const int px = tl & 31, ic8 = tl >> 5;
    if (px < 25) {
      const int y = px / 5, xx = px - y * 5;
      float pacc[8] = {0,0,0,0,0,0,0,0};
      const float4* pw34 = (const float4*)pw3;
#pragma unroll
      for (int i = 0; i < 4; i++) {
        const int icg = ic8 * 4 + i;
        float rr[9];
#pragma unroll
        for (int ky = 0; ky < 3; ky++) {
          const int base = C2S + icg * 56 + (y + ky) * 8 + xx;
          rr[ky * 3 + 0] = SA[base];
          rr[ky * 3 + 1] = SA[base + 1];
          rr[ky * 3 + 2] = SA[base + 2];
        }
#pragma unroll
        for (int oc = 0; oc < 8; oc++) {
          const float4 f0 = pw34[(icg * 8 + oc) * 3 + 0];
          const float4 f1 = pw34[(icg * 8 + oc) * 3 + 1];
          const float4 f2 = pw34[(icg * 8 + oc) * 3 + 2];
          pacc[oc] = fmaf(rr[0], f0.x, fmaf(rr[1], f0.y, fmaf(rr[2], f0.z,
                     fmaf(rr[3], f0.w, fmaf(rr[4], f1.x, fmaf(rr[5], f1.y,
                     fmaf(rr[6], f1.z, fmaf(rr[7], f1.w,
                     fmaf(rr[8], f2.x, pacc[oc])))))))));
        }
      }
      float* wpp = &SA[P6 + px * 64 + ic8 * 8];
#pragma unroll
      for (int oc = 0; oc < 8; oc++) wpp[oc] = pacc[oc];
    }
  }
  __syncthreads();
  if (tl < 200) {
    const int oc = tl & 7, px = tl >> 3;
    float s = b3[oc];
    const float* rp = &SA[P6 + px * 64 + oc];
#pragma unroll
    for (int g = 0; g < 8; g++) s += rp[g * 8];
    SA[C3S + oc * 25 + px] = lrelu(s);
  }
  __syncthreads();

  // ---- stage 7: dense 200->64 partials, 4 chunks (56/56/56/32), float4 ----
  {
    const int o = tl & 63, chunk = tl >> 6;
    const int start = chunk * 56;
    const int cnt = (chunk == 3) ? 8 : 14;
    const float4* wr4 = (const float4*)&dw1[o * 200 + start];
    const float4* cr4 = (const float4*)&SA[C3S + start];
    float acc = 0.f;
    for (int i = 0; i < cnt; i++) {   // runtime bound OK: memory only
      const float4 wv = wr4[i], cv = cr4[i];
      acc += wv.x * cv.x + wv.y * cv.y + wv.z * cv.z + wv.w * cv.w;
    }
    SA[D1P + chunk * 64 + o] = acc;
  }
  __syncthreads();

  // ---- dense head: ONE wave per patch (R9: waves 0 and 4); unroll 4 (R22) ----
  if (tl < 64) {
    SA[D1 + tl] = lrelu(SA[D1P + tl] + SA[D1P + 64 + tl] + SA[D1P + 128 + tl] +
                        SA[D1P + 192 + tl] + db1[tl]);
    __builtin_amdgcn_s_waitcnt(0); __builtin_amdgcn_wave_barrier();
    if (tl < 32) {
      float acc = db2[tl];
      const float4* wr = (const float4*)&dw2[tl * 64];
      const float4* dr = (const float4*)&SA[D1];
#pragma unroll 4
      for (int i = 0; i < 16; i++) acc = fma4(wr[i], dr[i], acc);
      SA[D2 + tl] = lrelu(acc);
    }
    __builtin_amdgcn_s_waitcnt(0); __builtin_amdgcn_wave_barrier();
    if (tl < 16) {
      float acc = db3[tl];
      const float4* wr = (const float4*)&dw3[tl * 32];
      const float4* dr = (const float4*)&SA[D2];
#pragma unroll 4
      for (int i = 0; i < 8; i++) acc = fma4(wr[i], dr[i], acc);
      SA[D3 + tl] = lrelu(acc);
    }
    __builtin_amdgcn_s_waitcnt(0); __builtin_amdgcn_wave_barrier();
    if (tl < 8) {
      float acc = db4[tl];
      const float4* wr = (const float4*)&dw4[tl * 16];
      const float4* dr = (const float4*)&SA[D3];
#pragma unroll
      for (int i = 0; i < 4; i++) acc = fma4(wr[i], dr[i], acc);
      SA[D4 + tl] = lrelu(acc);
    }
    __builtin_amdgcn_s_waitcnt(0); __builtin_amdgcn_wave_barrier();
    if (tl < 2 && pvalid) {
      float acc = db5[tl];
      const float4* wr = (const float4*)&dw5[tl * 8];
      const float4* dr = (const float4*)&SA[D4];
#pragma unroll
      for (int i = 0; i < 2; i++) acc = fma4(wr[i], dr[i], acc);
      out[(size_t)p * 2 + tl] = acc;
    }
  }
}

extern "C" void kernel_launch(void* const* d_in, const int* in_sizes, int n_in,
                              void* d_out, int out_size, void* d_ws, size_t ws_size,
                              hipStream_t stream) {
  const float* x   = (const float*)d_in[0];
  const float* w1  = (const float*)d_in[1];
  const float* b1  = (const float*)d_in[2];
  const float* wt  = (const float*)d_in[3];
  const float* bt  = (const float*)d_in[4];
  const float* wp  = (const float*)d_in[5];
  const float* bp  = (const float*)d_in[6];
  const float* wg  = (const float*)d_in[7];
  const float* bg  = (const float*)d_in[8];
  const float* wo  = (const float*)d_in[9];
  const float* bo  = (const float*)d_in[10];
  const float* w2  = (const float*)d_in[11];
  const float* b2  = (const float*)d_in[12];
  const float* w3  = (const float*)d_in[13];
  const float* b3  = (const float*)d_in[14];
  const float* dw1 = (const float*)d_in[15];
  const float* db1 = (const float*)d_in[16];
  const float* dw2 = (const float*)d_in[17];
  const float* db2 = (const float*)d_in[18];
  const float* dw3 = (const float*)d_in[19];
  const float* db3 = (const float*)d_in[20];
  const float* dw4 = (const float*)d_in[21];
  const float* db4 = (const float*)d_in[22];
  const float* dw5 = (const float*)d_in[23];
  const float* db5 = (const float*)d_in[24];

  float* pw = (float*)d_ws;   // wb2@0 | pw3@9216 | wtpg@12288 | wob@15360
  repack_w23<<<32, 256, 0, stream>>>(w2, w3, wt, wp, wg, wo, pw);
  const u16* wb2 = (const u16*)pw;
  const float* pw3 = pw + 9216;
  const u16* wtpg = (const u16*)(pw + 12288);
  const u16* wob = (const u16*)(pw + 15360);

  int B = in_sizes[0] / 121;
  int grid = (B + 1) / 2;
  braggnn_fused<<<grid, 512, 0, stream>>>(
      x, w1, b1, wtpg, bt, bp, bg, wob, bo, wb2, pw3, b2, b3,
      dw1, db1, dw2, db2, dw3, db3, dw4, db4, dw5, db5,
      (float*)d_out, B);
}

// Round 14
// 611.294 us; speedup vs baseline: 1.2655x; 1.2655x over previous
//
#include <hip/hip_runtime.h>

#define NEG 0.01f
__device__ __forceinline__ float lrelu(float v){ return v >= 0.f ? v : NEG * v; }

typedef short bf16x8 __attribute__((ext_vector_type(8)));   // 8 bf16 = 4 VGPRs
typedef float f32x4 __attribute__((ext_vector_type(4)));
typedef unsigned short u16;

__device__ __forceinline__ u16 f2bf(float f) {   // RNE f32 -> bf16 (finite inputs)
  unsigned u = __float_as_uint(f);
  return (u16)((u + 0x7FFFu + ((u >> 16) & 1u)) >> 16);
}
__device__ __forceinline__ float bflo(unsigned u){ return __uint_as_float(u << 16); }
__device__ __forceinline__ float bfhi(unsigned u){ return __uint_as_float(u & 0xffff0000u); }
__device__ __forceinline__ float bfu(u16 v){ return __uint_as_float((unsigned)v << 16); }

__device__ __forceinline__ float fma4(float4 wv, float4 hv, float acc) {
  return fmaf(wv.x, hv.x, fmaf(wv.y, hv.y, fmaf(wv.z, hv.z, fmaf(wv.w, hv.w, acc))));
}

// ============================ RULES (carried) ============================
// (R2)  no runtime-bound loop may index a register array — full unroll only.
// (R9)  dense head in wave 0 only (s_waitcnt+wave_barrier ordering).
// (R14) MFMA 16x16x32 bf16 map (verified): A row m=l&15, k=8*(l>>4)+i; B col
//       n=l&15; C/D row=(l>>4)*4+reg, col=l&15. Garbage rows safe (discard).
// (R15) H2 bf16 from birth; residual rounds ONCE.
// (R16) VGPR cliff at 64. PROVEN r11/r12: nothing live across barriers + hard
//       cap -> 44 VGPR, no spill. Keep both.
// (R20) serial p-loops: zero overlap (r4). (R31-b) paired-patch 512-thr
//       blocks: NEGATIVE (r13, 673->717; wider barriers + occ drop). Reverted.
// (R22) unroll-1 on HOT weight loops serializes latency; dense head unroll 4.
// (R24) stage-2a = MFMA GEMM [81x64]x[64x96] (T|P|G); G -> LDS bf16 stash.
// (R25) H2B row stride 36 u32 (144B): MFMA A-reads ~2-way; st-1 writes <=2-way.
// (R26) split retired (r7). (R27) stash regions FULL size (r8 bug).
// (R28) stage-4 = MFMA [81x32]x[32x64]; A = bf16(attn*G) built in-reg.
// (R29) stage-4 BARRIER-FREE: in-place H2B RMW on wave-own rows.
// (R30) SBH/G bf16 [81][40]: arena 6156 dw.
// (R32) LIMITER MODEL (fits r0-r13): dur = per-CU TOTAL-ISSUE floor; pinned
//       vs occupancy (r12: +21% C -> 0%), vs barriers (r13), vs latency.
//       Only lever that ever moved dur: deleting issued instructions
//       (r1/r7/r10). So: delete instructions.
// (R33) stage-6 = MFMA: conv3 [25px x K=288] x [288 x 8oc]; ic-fastest im2col
//       -> each tap = ONE K=32 MFMA; 9 MFMA/m-tile, m-tiles {0,1} on waves
//       {0,1}. C2S stored bf16 [56 rows][40 u16] (pad: banks (row*20+kg*4)%32
//       -> 2-way; byte 80*row+16*kg -> 16B aligned). Deletes 288 fma/thread,
//       P6 round-trip, t<200 reduce, and 1 barrier. Conv3 input now bf16.

// -------- LDS arena: S[6156] dw = 24624 B -> 6 blocks/CU --------
// Phase A (0-4): H2B@0 u32[81][36] (2916) | SBH@2916 u16[81][40] (1620) |
//   XS@4536(121, dies st-1) | G@4536 u16[81][40] (1620, born 2a after XS dead).
// Stage 4: in-place H2B->H4 u16[81][72] @0 (R29, no barrier).
// Stage 5: A-reads H4@0 stride 144B (garbage rows <=101 -> dw <=3676,
//   in-arena, values irrelevant), writes C2S@2916 u16[56][40] (1120 dw,
//   dw 2916..4035, over dead SBH+G head).
// Stage 6 (R33): reads C2S@2916 (clamped rows, all in-region), writes
//   C3S@1600 (200 dw over dead H4).
// Phase C: C3S@1600(200) D1P@1800(256) D1@2056 D2@2120 D3@2152 D4@2168.
#define H2B  0
#define SBH  2916
#define XS   4536
#define G0   4536
#define H4   0
#define C2S  2916
#define C3S  1600
#define D1P  1800
#define D1   2056
#define D2   2120
#define D3   2152
#define D4   2168

// repack (all bf16 u16): wb2 [tap9][oc32][ic64] @u16 0 (18432)
//   wtpg [96 n][64 k] @u16 18432 (6144) | wob [64 n][32 k] @u16 24576 (2048)
//   wb3b [tap9][16 n][32 k] @u16 26624 (4608; n>=8 zero)   total 31232 u16
__global__ void repack_w23(const float* __restrict__ w2, const float* __restrict__ w3,
                           const float* __restrict__ wt, const float* __restrict__ wp,
                           const float* __restrict__ wg, const float* __restrict__ wo,
                           float* __restrict__ pw) {
  int idx = blockIdx.x * 256 + threadIdx.x;
  u16* u = (u16*)pw;
  for (int i = idx; i < 31232; i += gridDim.x * 256) {
    if (i < 18432) {
      int ic = i & 63, oc = (i >> 6) & 31, tap = i >> 11;
      u[i] = f2bf(w2[(oc * 64 + ic) * 9 + tap]);
    } else if (i < 24576) {
      int j = i - 18432;                 // wtpg
      int k = j & 63, n = j >> 6;
      float v = (n < 32) ? wt[n * 64 + k]
              : (n < 64) ? wp[(n - 32) * 64 + k]
                         : wg[(n - 64) * 64 + k];
      u[i] = f2bf(v);
    } else if (i < 26624) {
      int j = i - 24576;                 // wob: [oc][ic]
      u[i] = f2bf(wo[j]);
    } else {
      int j = i - 26624;                 // wb3b: [tap][16 n][32 ic]
      int ic = j & 31, n = (j >> 5) & 15, tap = j >> 9;
      u[i] = (n < 8) ? f2bf(w3[(n * 32 + ic) * 9 + tap]) : (u16)0;
    }
  }
}

// stage-4 A-fragment: bf16(attn*G), both operands bf16 in LDS (R28/R30)
__device__ __forceinline__ bf16x8 st4_afrag(const float* S, int ar, int kg) {
  const uint4 sv = *(const uint4*)((const u16*)&S[SBH] + ar * 40 + kg * 8);
  const uint4 gv = *(const uint4*)((const u16*)&S[G0] + ar * 40 + kg * 8);
  unsigned q0 = (unsigned)f2bf(bflo(sv.x) * bflo(gv.x)) |
                ((unsigned)f2bf(bfhi(sv.x) * bfhi(gv.x)) << 16);
  unsigned q1 = (unsigned)f2bf(bflo(sv.y) * bflo(gv.y)) |
                ((unsigned)f2bf(bfhi(sv.y) * bfhi(gv.y)) << 16);
  unsigned q2 = (unsigned)f2bf(bflo(sv.z) * bflo(gv.z)) |
                ((unsigned)f2bf(bfhi(sv.z) * bfhi(gv.z)) << 16);
  unsigned q3 = (unsigned)f2bf(bflo(sv.w) * bflo(gv.w)) |
                ((unsigned)f2bf(bfhi(sv.w) * bfhi(gv.w)) << 16);
  union { uint4 u; bf16x8 b; } v; v.u = (uint4){q0, q1, q2, q3}; return v.b;
}

__global__ __launch_bounds__(256, 8) __attribute__((amdgpu_num_vgpr(64)))
void braggnn_fused(
    const float* __restrict__ x,
    const float* __restrict__ w1, const float* __restrict__ b1,
    const u16* __restrict__ wtpg,
    const float* __restrict__ bt, const float* __restrict__ bp,
    const float* __restrict__ bg,
    const u16* __restrict__ wob, const float* __restrict__ bo,
    const u16* __restrict__ wb2, const u16* __restrict__ wb3b,
    const float* __restrict__ b2, const float* __restrict__ b3,
    const float* __restrict__ dw1, const float* __restrict__ db1,
    const float* __restrict__ dw2, const float* __restrict__ db2,
    const float* __restrict__ dw3, const float* __restrict__ db3,
    const float* __restrict__ dw4, const float* __restrict__ db4,
    const float* __restrict__ dw5, const float* __restrict__ db5,
    float* __restrict__ out)
{
  const int b = blockIdx.x;
  const int t = threadIdx.x;

  __shared__ __align__(16) float S[6156];   // 24624 B

  // ---- stage 0: load 11x11 patch ----
  if (t < 121) S[XS + t] = x[(size_t)b * 121 + t];
  __syncthreads();

  // ---- stage 1: conv1 1->64 3x3, oc-PAIRED -> H2B bf16 [81][72s36] (R15/R25) ----
  {
    const int ocp = t & 31, pg = t >> 5;       // oc = 2*ocp, 2*ocp+1; pg 0..7
    float wreg[18];
#pragma unroll
    for (int i = 0; i < 18; i++) wreg[i] = w1[ocp * 18 + i];
    const float bv0 = b1[2 * ocp], bv1 = b1[2 * ocp + 1];
    for (int px = pg; px < 81; px += 8) {
      const int y = px / 9, xx = px - y * 9;
      const float* xr = &S[XS + y * 11 + xx];
      float a0 = bv0, a1 = bv1;
#pragma unroll
      for (int ky = 0; ky < 3; ky++)
#pragma unroll
        for (int kx = 0; kx < 3; kx++) {
          const float v = xr[ky * 11 + kx];
          a0 = fmaf(v, wreg[ky * 3 + kx], a0);
          a1 = fmaf(v, wreg[9 + ky * 3 + kx], a1);
        }
      ((unsigned*)S)[H2B + px * 36 + ocp] =
          (unsigned)f2bf(a0) | ((unsigned)f2bf(a1) << 16);
    }
  }
  __syncthreads();

  // ---- stage 2a (R24): theta/phi/g via MFMA; logits -> SBH bf16, g -> G ----
  {
    const int lane = t & 63, wid = t >> 6;
    const int c = lane & 15, kg = lane >> 4;
    const char* Sb = (const char*)S;          // H2B at byte 0, 144 B/row
    u16* SBu = (u16*)&S[SBH];
    u16* Gp  = (u16*)&S[G0];
#pragma unroll 1
    for (int r2 = 0; r2 < 2; r2++) {
      const int mt = wid + 4 * r2;
      if (mt >= 6) break;                     // wave-uniform
      const int arow = mt * 16 + c;           // px (rows 81-95: garbage, discarded)
      const bf16x8 a0 = *(const bf16x8*)(Sb + arow * 144 + kg * 16);
      const bf16x8 a1 = *(const bf16x8*)(Sb + arow * 144 + 64 + kg * 16);
#pragma unroll
      for (int ng = 0; ng < 2; ng++) {
        const u16* bl = wtpg + (ng * 16 + c) * 64 + kg * 8;
        const bf16x8 t0 = *(const bf16x8*)(bl);
        const bf16x8 t1 = *(const bf16x8*)(bl + 32);
        const bf16x8 p0 = *(const bf16x8*)(bl + 2048);       // +32 n
        const bf16x8 p1 = *(const bf16x8*)(bl + 2048 + 32);
        const bf16x8 g0 = *(const bf16x8*)(bl + 4096);       // +64 n
        const bf16x8 g1 = *(const bf16x8*)(bl + 4096 + 32);
        f32x4 aT = {0.f,0.f,0.f,0.f}, aP = {0.f,0.f,0.f,0.f}, aG = {0.f,0.f,0.f,0.f};
        aT = __builtin_amdgcn_mfma_f32_16x16x32_bf16(a0, t0, aT, 0, 0, 0);
        aT = __builtin_amdgcn_mfma_f32_16x16x32_bf16(a1, t1, aT, 0, 0, 0);
        aP = __builtin_amdgcn_mfma_f32_16x16x32_bf16(a0, p0, aP, 0, 0, 0);
        aP = __builtin_amdgcn_mfma_f32_16x16x32_bf16(a1, p1, aP, 0, 0, 0);
        aG = __builtin_amdgcn_mfma_f32_16x16x32_bf16(a0, g0, aG, 0, 0, 0);
        aG = __builtin_amdgcn_mfma_f32_16x16x32_bf16(a1, g1, aG, 0, 0, 0);
        const int oc = ng * 16 + c;
        const float bT = bt[oc], bP = bp[oc], bG = bg[oc];
#pragma unroll
        for (int r = 0; r < 4; r++) {
          const int px = mt * 16 + kg * 4 + r;  // C row = (l>>4)*4 + reg (R14)
          if (px <= 80) {
            SBu[px * 40 + oc] = f2bf((aT[r] + bT) * (aP[r] + bP));   // R30
            Gp[px * 40 + oc]  = f2bf(aG[r] + bG);
          }
        }
      }
    }
  }
  __syncthreads();

  // ---- stage 2 pass B: softmax over W (9), bf16 in/out, f32 compute (R30) ----
  {
    u16* SBu = (u16*)&S[SBH];
    auto sm = [&](int r) {
      const int oc = r & 31, y = r >> 5;
      const int base = y * 9 * 40 + oc;       // u16 index; px = y*9+k
      float v[9]; float m = -1e30f;
#pragma unroll
      for (int k = 0; k < 9; k++) { v[k] = bfu(SBu[base + k * 40]); m = fmaxf(m, v[k]); }
      float s = 0.f;
#pragma unroll
      for (int k = 0; k < 9; k++) { v[k] = __expf(v[k] - m); s += v[k]; }
      const float inv = 1.f / s;
#pragma unroll
      for (int k = 0; k < 9; k++) SBu[base + k * 40] = f2bf(v[k] * inv);
    };
    sm(t);
    if (t < 32) sm(256 + t);
  }
  __syncthreads();

  // ---- stage 4 (R28/R29): wo 1x1 as MFMA, BARRIER-FREE, in-place H2B RMW ----
  {
    const int lane = t & 63, wid = t >> 6;
    const int c = lane & 15, kg = lane >> 4;
    const u16* wbp = wob + c * 32 + kg * 8;
    const bf16x8 b0 = *(const bf16x8*)(wbp);
    const bf16x8 b1 = *(const bf16x8*)(wbp + 512);    // +16 n
    const bf16x8 b2v = *(const bf16x8*)(wbp + 1024);  // +32 n
    const bf16x8 b3v = *(const bf16x8*)(wbp + 1536);  // +48 n
    const f32x4 z = {0.f, 0.f, 0.f, 0.f};
    u16* Hw = (u16*)S;      // H2B/H4 u16 view: idx = px*72 + oc (same address!)
#define ST4EPI(MT, ACC, NT) { \
      const int oc_ = (NT) * 16 + c; \
      const float bov_ = bo[oc_]; \
      _Pragma("unroll") \
      for (int r = 0; r < 4; r++) { \
        const int px_ = (MT) * 16 + kg * 4 + r; \
        if (px_ <= 80) { \
          const int idx_ = px_ * 72 + oc_; \
          Hw[idx_] = f2bf(lrelu((ACC[r] + bfu(Hw[idx_])) + bov_)); \
        } \
      } }
    {   // m-tile 0: rows [16*wid, 16*wid+16) — own rows only (R29)
      const bf16x8 a0 = st4_afrag(S, wid * 16 + c, kg);
      f32x4 A0 = __builtin_amdgcn_mfma_f32_16x16x32_bf16(a0, b0, z, 0, 0, 0);
      f32x4 A1 = __builtin_amdgcn_mfma_f32_16x16x32_bf16(a0, b1, z, 0, 0, 0);
      f32x4 A2 = __builtin_amdgcn_mfma_f32_16x16x32_bf16(a0, b2v, z, 0, 0, 0);
      f32x4 A3 = __builtin_amdgcn_mfma_f32_16x16x32_bf16(a0, b3v, z, 0, 0, 0);
      ST4EPI(wid, A0, 0) ST4EPI(wid, A1, 1) ST4EPI(wid, A2, 2) ST4EPI(wid, A3, 3)
    }
    if (wid < 2) {   // m-tile 1: rows [16*(wid+4), ...) clamped to 80
      int ar1 = (wid + 4) * 16 + c; if (ar1 > 80) ar1 = 80;
      const bf16x8 a1 = st4_afrag(S, ar1, kg);
      f32x4 A0 = __builtin_amdgcn_mfma_f32_16x16x32_bf16(a1, b0, z, 0, 0, 0);
      f32x4 A1 = __builtin_amdgcn_mfma_f32_16x16x32_bf16(a1, b1, z, 0, 0, 0);
      f32x4 A2 = __builtin_amdgcn_mfma_f32_16x16x32_bf16(a1, b2v, z, 0, 0, 0);
      f32x4 A3 = __builtin_amdgcn_mfma_f32_16x16x32_bf16(a1, b3v, z, 0, 0, 0);
      const int mtB = wid + 4;
      ST4EPI(mtB, A0, 0) ST4EPI(mtB, A1, 1) ST4EPI(mtB, A2, 2) ST4EPI(mtB, A3, 3)
    }
  }
  __syncthreads();

  // ---- stage 5 (R14): conv2 64->32 3x3 as bf16 MFMA 16x16x32 ----
  {
    const int lane = t & 63, wid = t >> 6;
    const int m = lane & 15, kg = lane >> 4;      // A row, k-group
    const int opx = wid * 16 + m;                 // output px this lane feeds
    const int oy = opx / 7, ox = opx - oy * 7;
    const char* Sb = (const char*)S;
    int aoff = (oy * 9 + ox) * 144 + kg * 16;     // bytes into H4@0 (144 B/row)
    const u16* wbl = wb2 + (lane & 15) * 64 + kg * 8;
    f32x4 acc0 = {0.f, 0.f, 0.f, 0.f}, acc1 = {0.f, 0.f, 0.f, 0.f};
#pragma unroll 1
    for (int ky = 0; ky < 3; ky++) {
#pragma unroll
      for (int kx = 0; kx < 3; kx++) {
#pragma unroll
        for (int ks = 0; ks < 2; ks++) {
          const bf16x8 av = *(const bf16x8*)(Sb + (aoff + kx * 144 + ks * 64));
          const bf16x8 b0v = *(const bf16x8*)(wbl + kx * 2048 + ks * 32);
          const bf16x8 b1v = *(const bf16x8*)(wbl + kx * 2048 + ks * 32 + 1024);
          acc0 = __builtin_amdgcn_mfma_f32_16x16x32_bf16(av, b0v, acc0, 0, 0, 0);
          acc1 = __builtin_amdgcn_mfma_f32_16x16x32_bf16(av, b1v, acc1, 0, 0, 0);
        }
      }
      aoff += 9 * 144;        // next ky input row
      wbl  += 3 * 2048;       // next ky tap group
    }
    // epilogue (R33): bias + lrelu -> C2S bf16 [56 rows][40 u16] @2916
    // (over dead SBH+G head; garbage A-reads into this region are discarded).
    u16* C2u = (u16*)&S[C2S];
#pragma unroll
    for (int nt = 0; nt < 2; nt++) {
      const f32x4 accv = nt ? acc1 : acc0;
      const int oc = nt * 16 + (lane & 15);
      const float bv = b2[oc];
#pragma unroll
      for (int r = 0; r < 4; r++) {
        const int px = wid * 16 + kg * 4 + r;     // C row = (lane>>4)*4 + reg
        if (px < 49) {
          const int y = px / 7, xx = px - y * 7;
          C2u[(y * 8 + xx) * 40 + oc] = f2bf(lrelu(accv[r] + bv));
        }
      }
    }
  }
  __syncthreads();

  // ---- stage 6 (R33): conv3 32->8 3x3 as MFMA; 9 taps = 9 K=32 steps ----
  {
    const int lane = t & 63, wid = t >> 6;
    if (wid < 2) {
      const int c = lane & 15, kg = lane >> 4;
      int apx = wid * 16 + c; if (apx > 24) apx = 24;   // clamp garbage rows
      const int ay = apx / 5, ax = apx - ay * 5;
      const u16* C2u = (const u16*)&S[C2S];
      const u16* wb = wb3b + c * 32 + kg * 8;           // [tap][16 n][32 k]
      f32x4 acc = {0.f, 0.f, 0.f, 0.f};
#pragma unroll
      for (int ky = 0; ky < 3; ky++)
#pragma unroll
        for (int kx = 0; kx < 3; kx++) {
          const bf16x8 av = *(const bf16x8*)&C2u[((ay + ky) * 8 + (ax + kx)) * 40 + kg * 8];
          const bf16x8 bv = *(const bf16x8*)&wb[(ky * 3 + kx) * 512];
          acc = __builtin_amdgcn_mfma_f32_16x16x32_bf16(av, bv, acc, 0, 0, 0);
        }
      if (c < 8) {      // cols 8-15 are zero-weight garbage
        const float b3c = b3[c];
#pragma unroll
        for (int r = 0; r < 4; r++) {
          const int px = wid * 16 + kg * 4 + r;         // C row = kg*4+r
          if (px < 25) S[C3S + c * 25 + px] = lrelu(acc[r] + b3c);
        }
      }
    }
  }
  __syncthreads();

  // ---- stage 7: dense 200->64 partials, 4 chunks (56/56/56/32), float4 ----
  {
    const int o = t & 63, chunk = t >> 6;
    const int start = chunk * 56;
    const int cnt = (chunk == 3) ? 8 : 14;
    const float4* wr4 = (const float4*)&dw1[o * 200 + start];
    const float4* cr4 = (const float4*)&S[C3S + start];
    float acc = 0.f;
    for (int i = 0; i < cnt; i++) {   // runtime bound OK: memory only
      const float4 wv = wr4[i], cv = cr4[i];
      acc += wv.x * cv.x + wv.y * cv.y + wv.z * cv.z + wv.w * cv.w;
    }
    S[D1P + chunk * 64 + o] = acc;
  }
  __syncthreads();

  // ---- dense head: wave 0 only (R9); unroll 4 caps live float4s (R22) ----
  if (t < 64) {
    S[D1 + t] = lrelu(S[D1P + t] + S[D1P + 64 + t] + S[D1P + 128 + t] +
                      S[D1P + 192 + t] + db1[t]);
    __builtin_amdgcn_s_waitcnt(0); __builtin_amdgcn_wave_barrier();
    if (t < 32) {
      float acc = db2[t];
      const float4* wr = (const float4*)&dw2[t * 64];
      const float4* dr = (const float4*)&S[D1];
#pragma unroll 4
      for (int i = 0; i < 16; i++) acc = fma4(wr[i], dr[i], acc);
      S[D2 + t] = lrelu(acc);
    }
    __builtin_amdgcn_s_waitcnt(0); __builtin_amdgcn_wave_barrier();
    if (t < 16) {
      float acc = db3[t];
      const float4* wr = (const float4*)&dw3[t * 32];
      const float4* dr = (const float4*)&S[D2];
#pragma unroll 4
      for (int i = 0; i < 8; i++) acc = fma4(wr[i], dr[i], acc);
      S[D3 + t] = lrelu(acc);
    }
    __builtin_amdgcn_s_waitcnt(0); __builtin_amdgcn_wave_barrier();
    if (t < 8) {
      float acc = db4[t];
      const float4* wr = (const float4*)&dw4[t * 16];
      const float4* dr = (const float4*)&S[D3];
#pragma unroll
      for (int i = 0; i < 4; i++) acc = fma4(wr[i], dr[i], acc);
      S[D4 + t] = lrelu(acc);
    }
    __builtin_amdgcn_s_waitcnt(0); __builtin_amdgcn_wave_barrier();
    if (t < 2) {
      float acc = db5[t];
      const float4* wr = (const float4*)&dw5[t * 8];
      const float4* dr = (const float4*)&S[D4];
#pragma unroll
      for (int i = 0; i < 2; i++) acc = fma4(wr[i], dr[i], acc);
      out[(size_t)b * 2 + t] = acc;
    }
  }
}

extern "C" void kernel_launch(void* const* d_in, const int* in_sizes, int n_in,
                              void* d_out, int out_size, void* d_ws, size_t ws_size,
                              hipStream_t stream) {
  const float* x   = (const float*)d_in[0];
  const float* w1  = (const float*)d_in[1];
  const float* b1  = (const float*)d_in[2];
  const float* wt  = (const float*)d_in[3];
  const float* bt  = (const float*)d_in[4];
  const float* wp  = (const float*)d_in[5];
  const float* bp  = (const float*)d_in[6];
  const float* wg  = (const float*)d_in[7];
  const float* bg  = (const float*)d_in[8];
  const float* wo  = (const float*)d_in[9];
  const float* bo  = (const float*)d_in[10];
  const float* w2  = (const float*)d_in[11];
  const float* b2  = (const float*)d_in[12];
  const float* w3  = (const float*)d_in[13];
  const float* b3  = (const float*)d_in[14];
  const float* dw1 = (const float*)d_in[15];
  const float* db1 = (const float*)d_in[16];
  const float* dw2 = (const float*)d_in[17];
  const float* db2 = (const float*)d_in[18];
  const float* dw3 = (const float*)d_in[19];
  const float* db3 = (const float*)d_in[20];
  const float* dw4 = (const float*)d_in[21];
  const float* db4 = (const float*)d_in[22];
  const float* dw5 = (const float*)d_in[23];
  const float* db5 = (const float*)d_in[24];

  float* pw = (float*)d_ws;   // u16 layout: wb2@0 wtpg@18432 wob@24576 wb3b@26624
  repack_w23<<<32, 256, 0, stream>>>(w2, w3, wt, wp, wg, wo, pw);
  const u16* wb2  = (const u16*)pw;
  const u16* wtpg = (const u16*)(pw + 9216);
  const u16* wob  = (const u16*)(pw + 12288);
  const u16* wb3b = (const u16*)(pw + 13312);

  int B = in_sizes[0] / 121;
  braggnn_fused<<<B, 256, 0, stream>>>(
      x, w1, b1, wtpg, bt, bp, bg, wob, bo, wb2, wb3b, b2, b3,
      dw1, db1, dw2, db2, dw3, db3, dw4, db4, dw5, db5,
      (float*)d_out);
}